// Round 2
// 474.200 us; speedup vs baseline: 1.0353x; 1.0353x over previous
//
#include <hip/hip_runtime.h>

#define NUM_GRAPHS 512
#define EPS 1e-5f
#define CHN 128          // channels
#define CHN4 32          // channels as float4
#define RPB 256          // rows per block in normalize

typedef float f32x4 __attribute__((ext_vector_type(4)));   // clang vector: OK for NT builtins

__device__ __forceinline__ int lower_bound_i(const int* __restrict__ b, int n, int val) {
    int l = 0, r = n;
    while (l < r) {
        int m = (l + r) >> 1;
        if (b[m] < val) l = m + 1; else r = m;
    }
    return l;
}

// ---------------- k0: segment offsets (seg_off[s] = first row of segment s) ----
// 513 entries; batch is sorted. ~19 L2-resident dependent loads per thread.
__global__ __launch_bounds__(128) void gln_offsets(
    const int* __restrict__ batch, int* __restrict__ seg_off, int N)
{
    int s = blockIdx.x * 128 + threadIdx.x;
    if (s < NUM_GRAPHS)       seg_off[s] = lower_bound_i(batch, N, s);
    else if (s == NUM_GRAPHS) seg_off[s] = N;
}

// ---------------- k1: per-segment stats + finalize (fused) --------------------
// One block (1024 threads) per segment: streams the segment's contiguous rows
// (32 rows / 16 KB in flight per iteration, perfectly coalesced), LDS tree
// reduction, then computes scale/shift directly. 512 blocks = 2/CU, one round.
__global__ __launch_bounds__(1024) void gln_stats(
    const float* __restrict__ x,
    const int* __restrict__ seg_off,
    const float* __restrict__ weight,
    const float* __restrict__ bias,
    float* __restrict__ ws_stats)
{
    const int s   = blockIdx.x;
    const int tid = threadIdx.x;
    const int q   = tid & 31;          // float4 column
    const int g   = tid >> 5;          // row group 0..31

    const int lo = seg_off[s];
    const int hi = seg_off[s + 1];

    const float4* __restrict__ x4 = (const float4*)x;

    float4 sum = make_float4(0.f, 0.f, 0.f, 0.f);
    float4 sq  = make_float4(0.f, 0.f, 0.f, 0.f);
    for (int r = lo + g; r < hi; r += 32) {
        float4 v = x4[(size_t)r * CHN4 + q];
        sum.x += v.x; sum.y += v.y; sum.z += v.z; sum.w += v.w;
        sq.x  += v.x * v.x; sq.y += v.y * v.y; sq.z += v.z * v.z; sq.w += v.w * v.w;
    }

    __shared__ float4 s_sum[1024];
    __shared__ float4 s_sq[1024];
    s_sum[tid] = sum; s_sq[tid] = sq;
    __syncthreads();

    #pragma unroll
    for (int off = 512; off >= 32; off >>= 1) {
        if (tid < off) {
            float4 a = s_sum[tid], b = s_sum[tid + off];
            a.x += b.x; a.y += b.y; a.z += b.z; a.w += b.w;
            s_sum[tid] = a;
            float4 c = s_sq[tid], d = s_sq[tid + off];
            c.x += d.x; c.y += d.y; c.z += d.z; c.w += d.w;
            s_sq[tid] = c;
        }
        __syncthreads();
    }

    if (tid < CHN) {
        // s_sum[0..31] as flat floats == per-channel sums (channel c = tid)
        float sum_c = ((const float*)s_sum)[tid];
        float sq_c  = ((const float*)s_sq)[tid];
        float inv_cnt = 1.f / fmaxf((float)(hi - lo), 1.f);
        float mean    = sum_c * inv_cnt;
        float inv_std = rsqrtf(sq_c * inv_cnt - mean * mean + EPS);
        float scale = inv_std * weight[tid];
        float shift = bias[tid] - mean * scale;
        ws_stats[(size_t)s * 256 + tid]       = scale;
        ws_stats[(size_t)s * 256 + 128 + tid] = shift;
    }
}

// ---------------- k2: normalize -----------------------------------------------
// Block handles RPB consecutive rows; thread owns float4-column q and walks rows
// with stride 8. scale/shift and the current segment's end row live in REGISTERS
// and are only reloaded when the walk crosses a segment boundary (~every 977
// rows), so the steady state is 1 NT load + 4 FMA + 1 NT store per float4.
// NT hints keep x resident in the 256 MB L3 (it was just streamed by k1) by not
// letting the output writes evict it.
__global__ __launch_bounds__(256) void gln_normalize(
    const float* __restrict__ x,
    const int* __restrict__ batch,
    const int* __restrict__ seg_off,
    const float* __restrict__ ws_stats,
    float* __restrict__ out, int N)
{
    const int tid = threadIdx.x;
    const int q   = tid & 31;          // float4 column
    const int g   = tid >> 5;          // row group 0..7

    const int row0 = blockIdx.x * RPB + g;
    const int rend = min(blockIdx.x * RPB + RPB, N);
    if (row0 >= rend) return;

    int seg = batch[row0];
    int hi  = seg_off[seg + 1];

    const float4* __restrict__ st4 = (const float4*)ws_stats;
    float4 sc = st4[(size_t)seg * 64 + q];
    float4 sh = st4[(size_t)seg * 64 + 32 + q];

    const f32x4* __restrict__ x4 = (const f32x4*)x;
    f32x4* __restrict__ o4       = (f32x4*)out;

    for (int r = row0; r < rend; r += 8) {
        while (r >= hi) {                      // crossed into next segment
            ++seg;
            hi = seg_off[seg + 1];
            sc = st4[(size_t)seg * 64 + q];
            sh = st4[(size_t)seg * 64 + 32 + q];
        }
        const f32x4 v = __builtin_nontemporal_load(x4 + ((size_t)r * CHN4 + q));
        f32x4 o;
        o.x = fmaf(v.x, sc.x, sh.x);
        o.y = fmaf(v.y, sc.y, sh.y);
        o.z = fmaf(v.z, sc.z, sh.z);
        o.w = fmaf(v.w, sc.w, sh.w);
        __builtin_nontemporal_store(o, o4 + ((size_t)r * CHN4 + q));
    }
}

extern "C" void kernel_launch(void* const* d_in, const int* in_sizes, int n_in,
                              void* d_out, int out_size, void* d_ws, size_t ws_size,
                              hipStream_t stream) {
    const float* x      = (const float*)d_in[0];
    const int*   batch  = (const int*)d_in[1];
    const float* weight = (const float*)d_in[2];
    const float* bias   = (const float*)d_in[3];
    float*       out    = (float*)d_out;
    const int N = in_sizes[0] / CHN;   // 500000

    int*   seg_off  = (int*)d_ws;                       // 513 ints (pad to 4 KB)
    float* ws_stats = (float*)((char*)d_ws + 4096);     // 512*256 floats = 512 KB

    gln_offsets<<<(NUM_GRAPHS + 1 + 127) / 128, 128, 0, stream>>>(batch, seg_off, N);
    gln_stats<<<NUM_GRAPHS, 1024, 0, stream>>>(x, seg_off, weight, bias, ws_stats);
    gln_normalize<<<(N + RPB - 1) / RPB, 256, 0, stream>>>(x, batch, seg_off, ws_stats, out, N);
}

// Round 3
// 462.921 us; speedup vs baseline: 1.0605x; 1.0244x over previous
//
#include <hip/hip_runtime.h>

#define NUM_GRAPHS 512
#define EPS 1e-5f
#define CHN 128          // channels
#define CHN4 32          // channels as float4
#define TPB 1024         // threads per block (16 waves); 512 blocks = exactly 2/CU

typedef float f32x4 __attribute__((ext_vector_type(4)));   // clang vector: OK for NT builtins

// Wave-parallel 64-ary lower_bound: each round all 64 lanes probe, ballot picks
// the subrange. ~5 rounds for N=500000 (vs 19 serial dependent loads for binary
// search). Wave-uniform control flow; every wave of the block runs it
// redundantly (identical result, probes coalesce in L1/L2).
__device__ __forceinline__ int wave_lower_bound(const int* __restrict__ b, int n, int val) {
    int lo = 0, hi = n;                       // invariant: b[lo-1] < val, b[hi] >= val (virtual)
    const int lane = threadIdx.x & 63;
    while (hi > lo) {
        const int len  = hi - lo;
        const int step = (len + 63) >> 6;     // ceil(len/64)
        const int pos  = lo + lane * step;    // lane 0 probes lo
        const bool p   = (pos < hi) && (b[pos] < val);
        const unsigned long long m = __ballot(p);
        if (m == 0ULL) return lo;             // b[lo] >= val -> answer is lo
        const int k = 63 - __clzll(m);        // highest lane with b[pos] < val
        lo = lo + k * step + 1;               // b[pos_k] < val -> lower_bound > pos_k
        const int nhi = lo - 1 + step;        // pos_{k+1}
        hi = (nhi < hi) ? nhi : hi;
    }
    return lo;
}

// ---------------- single fused kernel: one block per segment ------------------
// pass 1: stream segment rows (plain loads -> populate L3), accumulate sum/sumsq
// LDS tree-reduce -> per-channel scale/shift in LDS
// pass 2: re-read segment rows (L3-warm), fma, NT store (don't evict x from L3)
__global__ __launch_bounds__(TPB) void gln_fused(
    const float* __restrict__ x,
    const int* __restrict__ batch,
    const float* __restrict__ weight,
    const float* __restrict__ bias,
    float* __restrict__ out, int N)
{
    const int s   = blockIdx.x;
    const int tid = threadIdx.x;
    const int q   = tid & 31;          // float4 column
    const int g   = tid >> 5;          // row group 0..31

    const int lo = wave_lower_bound(batch, N, s);
    const int hi = wave_lower_bound(batch, N, s + 1);

    const float4* __restrict__ x4 = (const float4*)x;

    float4 sum = make_float4(0.f, 0.f, 0.f, 0.f);
    float4 sq  = make_float4(0.f, 0.f, 0.f, 0.f);
    for (int r = lo + g; r < hi; r += 32) {
        float4 v = x4[(size_t)r * CHN4 + q];
        sum.x += v.x; sum.y += v.y; sum.z += v.z; sum.w += v.w;
        sq.x  += v.x * v.x; sq.y += v.y * v.y; sq.z += v.z * v.z; sq.w += v.w * v.w;
    }

    __shared__ float4 s_sum[TPB];
    __shared__ float4 s_sq[TPB];
    s_sum[tid] = sum; s_sq[tid] = sq;
    __syncthreads();

    #pragma unroll
    for (int off = 512; off >= 32; off >>= 1) {
        if (tid < off) {
            float4 a = s_sum[tid], b = s_sum[tid + off];
            a.x += b.x; a.y += b.y; a.z += b.z; a.w += b.w;
            s_sum[tid] = a;
            float4 c = s_sq[tid], d = s_sq[tid + off];
            c.x += d.x; c.y += d.y; c.z += d.z; c.w += d.w;
            s_sq[tid] = c;
        }
        __syncthreads();
    }

    __shared__ float s_scale[CHN];
    __shared__ float s_shift[CHN];
    if (tid < CHN) {
        // s_sum[0..31] as flat floats == per-channel sums (channel c = tid)
        float sum_c = ((const float*)s_sum)[tid];
        float sq_c  = ((const float*)s_sq)[tid];
        float inv_cnt = 1.f / fmaxf((float)(hi - lo), 1.f);
        float mean    = sum_c * inv_cnt;
        float inv_std = rsqrtf(sq_c * inv_cnt - mean * mean + EPS);
        float scale = inv_std * weight[tid];
        s_scale[tid] = scale;
        s_shift[tid] = bias[tid] - mean * scale;
    }
    __syncthreads();

    const float4 sc = ((const float4*)s_scale)[q];
    const float4 sh = ((const float4*)s_shift)[q];

    const f32x4* __restrict__ xx4 = (const f32x4*)x;
    f32x4* __restrict__ o4        = (f32x4*)out;
    for (int r = lo + g; r < hi; r += 32) {
        const f32x4 v = xx4[(size_t)r * CHN4 + q];   // plain load: allow L3 hit
        f32x4 o;
        o.x = fmaf(v.x, sc.x, sh.x);
        o.y = fmaf(v.y, sc.y, sh.y);
        o.z = fmaf(v.z, sc.z, sh.z);
        o.w = fmaf(v.w, sc.w, sh.w);
        __builtin_nontemporal_store(o, o4 + ((size_t)r * CHN4 + q));
    }
}

extern "C" void kernel_launch(void* const* d_in, const int* in_sizes, int n_in,
                              void* d_out, int out_size, void* d_ws, size_t ws_size,
                              hipStream_t stream) {
    const float* x      = (const float*)d_in[0];
    const int*   batch  = (const int*)d_in[1];
    const float* weight = (const float*)d_in[2];
    const float* bias   = (const float*)d_in[3];
    float*       out    = (float*)d_out;
    const int N = in_sizes[0] / CHN;   // 500000

    gln_fused<<<NUM_GRAPHS, TPB, 0, stream>>>(x, batch, weight, bias, out, N);
}

// Round 4
// 459.942 us; speedup vs baseline: 1.0674x; 1.0065x over previous
//
#include <hip/hip_runtime.h>

#define NUM_GRAPHS 512
#define EPS 1e-5f
#define CHN 128          // channels
#define CHN4 32          // channels as float4
#define TPB 1024         // threads per block (16 waves); 512 blocks = exactly 2/CU

typedef float f32x4 __attribute__((ext_vector_type(4)));   // clang vector: NT builtins + elementwise ops

// Wave-parallel 64-ary lower_bound: each round all 64 lanes probe, ballot picks
// the subrange. ~5 rounds for N=500000. Wave-uniform control flow; every wave
// runs it redundantly (identical result, probes coalesce in cache).
__device__ __forceinline__ int wave_lower_bound(const int* __restrict__ b, int n, int val) {
    int lo = 0, hi = n;
    const int lane = threadIdx.x & 63;
    while (hi > lo) {
        const int len  = hi - lo;
        const int step = (len + 63) >> 6;     // ceil(len/64)
        const int pos  = lo + lane * step;
        const bool p   = (pos < hi) && (b[pos] < val);
        const unsigned long long m = __ballot(p);
        if (m == 0ULL) return lo;
        const int k = 63 - __clzll(m);        // highest lane with b[pos] < val
        lo = lo + k * step + 1;
        const int nhi = lo - 1 + step;
        hi = (nhi < hi) ? nhi : hi;
    }
    return lo;
}

// ---------------- single fused kernel: one block per segment ------------------
// pass 1: stream segment rows (plain loads -> populate L3), sum/sumsq, 4-deep MLP
// LDS tree-reduce -> per-channel scale/shift in LDS
// pass 2: re-read rows (L3-warm), fma, NT store; 4-deep MLP
__global__ __launch_bounds__(TPB) void gln_fused(
    const float* __restrict__ x,
    const int* __restrict__ batch,
    const float* __restrict__ weight,
    const float* __restrict__ bias,
    float* __restrict__ out, int N)
{
    const int s   = blockIdx.x;
    const int tid = threadIdx.x;
    const int q   = tid & 31;          // float4 column
    const int g   = tid >> 5;          // row group 0..31

    const int lo = wave_lower_bound(batch, N, s);
    const int hi = wave_lower_bound(batch, N, s + 1);
    const int len = hi - lo;
    const int T   = len >> 7;          // full 128-row tiles (4 rows/thread/tile)

    const f32x4* __restrict__ x4 = (const f32x4*)x;

    f32x4 sum = {0.f, 0.f, 0.f, 0.f};
    f32x4 sq  = {0.f, 0.f, 0.f, 0.f};

    // ---- pass 1: 4 independent loads in flight per thread ----
    for (int t = 0; t < T; ++t) {
        const size_t base = (size_t)(lo + (t << 7) + g) * CHN4 + q;
        f32x4 v0 = x4[base];
        f32x4 v1 = x4[base + 32 * CHN4];
        f32x4 v2 = x4[base + 64 * CHN4];
        f32x4 v3 = x4[base + 96 * CHN4];
        sum += v0 + v1 + v2 + v3;
        sq  += v0 * v0 + v1 * v1 + v2 * v2 + v3 * v3;
    }
    for (int r = lo + (T << 7) + g; r < hi; r += 32) {   // tail (<128 rows)
        f32x4 v = x4[(size_t)r * CHN4 + q];
        sum += v;
        sq  += v * v;
    }

    __shared__ f32x4 s_sum[TPB];
    __shared__ f32x4 s_sq[TPB];
    s_sum[tid] = sum; s_sq[tid] = sq;
    __syncthreads();

    #pragma unroll
    for (int off = 512; off >= 32; off >>= 1) {
        if (tid < off) {
            s_sum[tid] += s_sum[tid + off];
            s_sq[tid]  += s_sq[tid + off];
        }
        __syncthreads();
    }

    __shared__ float s_scale[CHN];
    __shared__ float s_shift[CHN];
    if (tid < CHN) {
        // s_sum[0..31] as flat floats == per-channel sums (channel c = tid)
        float sum_c = ((const float*)s_sum)[tid];
        float sq_c  = ((const float*)s_sq)[tid];
        float inv_cnt = 1.f / fmaxf((float)len, 1.f);
        float mean    = sum_c * inv_cnt;
        float inv_std = rsqrtf(sq_c * inv_cnt - mean * mean + EPS);
        float scale = inv_std * weight[tid];
        s_scale[tid] = scale;
        s_shift[tid] = bias[tid] - mean * scale;
    }
    __syncthreads();

    const f32x4 sc = ((const f32x4*)s_scale)[q];
    const f32x4 sh = ((const f32x4*)s_shift)[q];

    f32x4* __restrict__ o4 = (f32x4*)out;

    // ---- pass 2: 4 loads issued, then 4 fma+NT-store ----
    for (int t = 0; t < T; ++t) {
        const size_t base = (size_t)(lo + (t << 7) + g) * CHN4 + q;
        f32x4 v0 = x4[base];
        f32x4 v1 = x4[base + 32 * CHN4];
        f32x4 v2 = x4[base + 64 * CHN4];
        f32x4 v3 = x4[base + 96 * CHN4];
        f32x4 o0 = v0 * sc + sh;
        f32x4 o1 = v1 * sc + sh;
        f32x4 o2 = v2 * sc + sh;
        f32x4 o3 = v3 * sc + sh;
        __builtin_nontemporal_store(o0, o4 + base);
        __builtin_nontemporal_store(o1, o4 + base + 32 * CHN4);
        __builtin_nontemporal_store(o2, o4 + base + 64 * CHN4);
        __builtin_nontemporal_store(o3, o4 + base + 96 * CHN4);
    }
    for (int r = lo + (T << 7) + g; r < hi; r += 32) {   // tail
        f32x4 v = x4[(size_t)r * CHN4 + q];
        f32x4 o = v * sc + sh;
        __builtin_nontemporal_store(o, o4 + ((size_t)r * CHN4 + q));
    }
}

extern "C" void kernel_launch(void* const* d_in, const int* in_sizes, int n_in,
                              void* d_out, int out_size, void* d_ws, size_t ws_size,
                              hipStream_t stream) {
    const float* x      = (const float*)d_in[0];
    const int*   batch  = (const int*)d_in[1];
    const float* weight = (const float*)d_in[2];
    const float* bias   = (const float*)d_in[3];
    float*       out    = (float*)d_out;
    const int N = in_sizes[0] / CHN;   // 500000

    gln_fused<<<NUM_GRAPHS, TPB, 0, stream>>>(x, batch, weight, bias, out, N);
}